// Round 3
// baseline (949.225 us; speedup 1.0000x reference)
//
#include <hip/hip_runtime.h>

#define F_IN 512
#define F_HID 16
#define F_OUT 7
#define BUCKET 256          // nodes per bucket (dl = dst & 255)
#define CHUNK 8192          // edges per partition block
#define AST 17              // LDS pad stride for 16-col acc tile
#define AST2 9              // LDS pad stride for 8-col acc tile

// ---------------- zero int array ----------------
__global__ void k_zero(int* __restrict__ p, int n) {
    int i = blockIdx.x * blockDim.x + threadIdx.x;
    if (i < n) p[i] = 0;
}

// ---------------- bucket histogram (per-block LDS, then global merge) ----------------
__global__ void k_bhist(const int* __restrict__ dst, int* __restrict__ bucket_cnt, int E, int NB) {
    __shared__ int hist[512];
    int t = threadIdx.x;
    for (int i = t; i < NB; i += 256) hist[i] = 0;
    __syncthreads();
    int base = blockIdx.x * CHUNK;
#pragma unroll
    for (int i = 0; i < CHUNK / 256; ++i) {
        int e = base + i * 256 + t;
        if (e < E) atomicAdd(&hist[dst[e] >> 8], 1);
    }
    __syncthreads();
    for (int i = t; i < NB; i += 256)
        if (hist[i]) atomicAdd(&bucket_cnt[i], hist[i]);
}

// ---------------- exclusive scan of bucket counts (1 block, NB<=512) ----------------
__global__ void k_bscan(const int* __restrict__ bucket_cnt, int* __restrict__ bucket_base,
                        int* __restrict__ cursor, int NB) {
    __shared__ int sm[512];
    int t = threadIdx.x;
    sm[t] = (t < NB) ? bucket_cnt[t] : 0;
    __syncthreads();
    for (int off = 1; off < 512; off <<= 1) {
        int v = sm[t];
        if (t >= off) v += sm[t - off];
        __syncthreads();
        sm[t] = v;
        __syncthreads();
    }
    if (t < NB) {
        int ex = (t == 0) ? 0 : sm[t - 1];
        bucket_base[t] = ex;
        cursor[t] = ex;
    }
}

// ---------------- partition: segmented placement of packed edges ----------------
__global__ void k_place(const int* __restrict__ src, const int* __restrict__ dst,
                        int* __restrict__ cursor, int* __restrict__ bedges, int E, int NB) {
    __shared__ int hist[512];
    __shared__ int lcur[512];
    int t = threadIdx.x;
    for (int i = t; i < NB; i += 256) hist[i] = 0;
    __syncthreads();
    int base = blockIdx.x * CHUNK;
#pragma unroll
    for (int i = 0; i < CHUNK / 256; ++i) {
        int e = base + i * 256 + t;
        if (e < E) atomicAdd(&hist[dst[e] >> 8], 1);
    }
    __syncthreads();
    for (int i = t; i < NB; i += 256)
        lcur[i] = hist[i] ? atomicAdd(&cursor[i], hist[i]) : 0;  // block's run start per bucket
    __syncthreads();
#pragma unroll
    for (int i = 0; i < CHUNK / 256; ++i) {
        int e = base + i * 256 + t;
        if (e < E) {
            int d = dst[e];
            int b = d >> 8;
            int pos = atomicAdd(&lcur[b], 1);
            bedges[pos] = (src[e] << 8) | (d & 255);   // src<2^17 -> fits with 8-bit dl
        }
    }
}

// ---------------- per-bucket degree histogram -> dinv ----------------
__global__ void k_bdeg_dinv(const int* __restrict__ bucket_base, const int* __restrict__ bucket_cnt,
                            const int* __restrict__ bedges, float* __restrict__ dinv, int n) {
    __shared__ int cnt[BUCKET];
    int b = blockIdx.x, t = threadIdx.x;
    cnt[t] = 0;
    __syncthreads();
    int start = bucket_base[b], ne = bucket_cnt[b];
    for (int j = t; j < ne; j += 256)
        atomicAdd(&cnt[bedges[start + j] & 255], 1);
    __syncthreads();
    int node = b * BUCKET + t;
    if (node < n) dinv[node] = rsqrtf((float)(cnt[t] + 1));   // +1 self-loop
}

// ---------------- GEMM1: h1s = dinv[r] * (x @ W1), one row per thread ----------------
__global__ void k_gemm1(const float* __restrict__ x, const float* __restrict__ W,
                        const float* __restrict__ dinv, float* __restrict__ h1s, int n) {
    int r = blockIdx.x * blockDim.x + threadIdx.x;
    if (r >= n) return;
    float acc[F_HID];
#pragma unroll
    for (int c = 0; c < F_HID; ++c) acc[c] = 0.0f;
    const float4* xr = (const float4*)(x + (size_t)r * F_IN);
    for (int k4 = 0; k4 < F_IN / 4; ++k4) {
        float4 xv = xr[k4];
        int k = k4 * 4;
#pragma unroll
        for (int c = 0; c < F_HID; ++c) {
            acc[c] = fmaf(xv.x, W[(k + 0) * F_HID + c], acc[c]);
            acc[c] = fmaf(xv.y, W[(k + 1) * F_HID + c], acc[c]);
            acc[c] = fmaf(xv.z, W[(k + 2) * F_HID + c], acc[c]);
            acc[c] = fmaf(xv.w, W[(k + 3) * F_HID + c], acc[c]);
        }
    }
    float dv = dinv[r];
    float4* o = (float4*)(h1s + (size_t)r * F_HID);
    o[0] = make_float4(dv * acc[0], dv * acc[1], dv * acc[2], dv * acc[3]);
    o[1] = make_float4(dv * acc[4], dv * acc[5], dv * acc[6], dv * acc[7]);
    o[2] = make_float4(dv * acc[8], dv * acc[9], dv * acc[10], dv * acc[11]);
    o[3] = make_float4(dv * acc[12], dv * acc[13], dv * acc[14], dv * acc[15]);
}

// ---------------- agg layer 1: block per bucket, LDS fp32 atomics, 16 lanes/edge ------
__global__ void k_agg1(const int* __restrict__ bucket_base, const int* __restrict__ bucket_cnt,
                       const int* __restrict__ bedges, const float* __restrict__ h1s,
                       const float* __restrict__ dinv, float* __restrict__ agg1, int n) {
    __shared__ float acc[BUCKET * AST];
    int b = blockIdx.x, t = threadIdx.x;             // 512 threads
    for (int i = t; i < BUCKET * AST; i += 512) acc[i] = 0.0f;
    __syncthreads();
    int start = bucket_base[b], ne = bucket_cnt[b];
    int c = t & 15, g = t >> 4;                      // 32 edge-groups of 16 lanes
    for (int j0 = 0; j0 < ne; j0 += 32) {
        int j = j0 + g;
        if (j < ne) {
            int p = bedges[start + j];
            int s = p >> 8, dl = p & 255;
            atomicAdd(&acc[dl * AST + c], h1s[(size_t)s * F_HID + c]);
        }
    }
    __syncthreads();
    int nodebase = b * BUCKET;
#pragma unroll
    for (int k = 0; k < 8; ++k) {
        int i = k * 512 + t;                         // 256*16 elements
        int row = i >> 4, cc = i & 15;
        int node = nodebase + row;
        if (node < n)
            agg1[(size_t)node * F_HID + cc] =
                dinv[node] * (acc[row * AST + cc] + h1s[(size_t)node * F_HID + cc]);
    }
}

// ---------------- relu+bias1+GEMM2, h2s = dinv * h2 (stride 8, col7 = 0) --------------
__global__ void k_layer2(const float* __restrict__ agg1, const float* __restrict__ b1,
                         const float* __restrict__ W2, const float* __restrict__ dinv,
                         float* __restrict__ h2s, int n) {
    int r = blockIdx.x * blockDim.x + threadIdx.x;
    if (r >= n) return;
    float z[F_HID];
    const float4* ai = (const float4*)(agg1 + (size_t)r * F_HID);
#pragma unroll
    for (int q = 0; q < 4; ++q) {
        float4 v = ai[q];
        z[q * 4 + 0] = fmaxf(v.x + b1[q * 4 + 0], 0.0f);
        z[q * 4 + 1] = fmaxf(v.y + b1[q * 4 + 1], 0.0f);
        z[q * 4 + 2] = fmaxf(v.z + b1[q * 4 + 2], 0.0f);
        z[q * 4 + 3] = fmaxf(v.w + b1[q * 4 + 3], 0.0f);
    }
    float h[F_OUT];
#pragma unroll
    for (int c = 0; c < F_OUT; ++c) h[c] = 0.0f;
#pragma unroll
    for (int k = 0; k < F_HID; ++k)
#pragma unroll
        for (int c = 0; c < F_OUT; ++c)
            h[c] = fmaf(z[k], W2[k * F_OUT + c], h[c]);
    float dv = dinv[r];
    float4* o = (float4*)(h2s + (size_t)r * 8);
    o[0] = make_float4(dv * h[0], dv * h[1], dv * h[2], dv * h[3]);
    o[1] = make_float4(dv * h[4], dv * h[5], dv * h[6], 0.0f);
}

// ---------------- agg layer 2: block per bucket, 8 lanes/edge, writes final out -------
__global__ void k_agg2(const int* __restrict__ bucket_base, const int* __restrict__ bucket_cnt,
                       const int* __restrict__ bedges, const float* __restrict__ h2s,
                       const float* __restrict__ dinv, const float* __restrict__ b2,
                       float* __restrict__ out, int n) {
    __shared__ float acc[BUCKET * AST2];
    int b = blockIdx.x, t = threadIdx.x;             // 512 threads
    for (int i = t; i < BUCKET * AST2; i += 512) acc[i] = 0.0f;
    __syncthreads();
    int start = bucket_base[b], ne = bucket_cnt[b];
    int c = t & 7, g = t >> 3;                       // 64 edge-groups of 8 lanes
    for (int j0 = 0; j0 < ne; j0 += 64) {
        int j = j0 + g;
        if (j < ne) {
            int p = bedges[start + j];
            int s = p >> 8, dl = p & 255;
            atomicAdd(&acc[dl * AST2 + c], h2s[(size_t)s * 8 + c]);
        }
    }
    __syncthreads();
    int nodebase = b * BUCKET;
#pragma unroll
    for (int k = 0; k < 4; ++k) {
        int i = k * 512 + t;                         // 256*8 elements
        int row = i >> 3, cc = i & 7;
        int node = nodebase + row;
        if (node < n && cc < F_OUT)
            out[(size_t)node * F_OUT + cc] =
                dinv[node] * (acc[row * AST2 + cc] + h2s[(size_t)node * 8 + cc]) + b2[cc];
    }
}

extern "C" void kernel_launch(void* const* d_in, const int* in_sizes, int n_in,
                              void* d_out, int out_size, void* d_ws, size_t ws_size,
                              hipStream_t stream) {
    const float* x  = (const float*)d_in[0];
    const int*   ei = (const int*)d_in[1];      // int64 in source but JAX x64 off -> int32
    const float* W1 = (const float*)d_in[2];
    const float* b1 = (const float*)d_in[3];
    const float* W2 = (const float*)d_in[4];
    const float* b2 = (const float*)d_in[5];
    float* out = (float*)d_out;

    const int n = in_sizes[0] / F_IN;       // 100000
    const int E = in_sizes[1] / 2;          // 3200000
    const int* src = ei;
    const int* dst = ei + E;

    const int NB = (n + BUCKET - 1) / BUCKET;   // 391 (must be <=512)
    const int PBLK = (E + CHUNK - 1) / CHUNK;   // 391 partition blocks

    // workspace layout
    size_t Np = ((size_t)n + 3) & ~(size_t)3;
    size_t Ep = ((size_t)E + 3) & ~(size_t)3;
    char* ws = (char*)d_ws;
    int*   bucket_cnt  = (int*)ws;              ws += 512 * 4;
    int*   bucket_base = (int*)ws;              ws += 512 * 4;
    int*   cursor      = (int*)ws;              ws += 512 * 4;
    float* dinv        = (float*)ws;            ws += Np * 4;
    int*   bedges      = (int*)ws;              ws += Ep * 4;
    float* h1s         = (float*)ws;            ws += Np * F_HID * 4;
    float* agg1        = (float*)ws;            ws += Np * F_HID * 4;
    float* h2s         = h1s;                   // h1s dead after k_agg1

    k_zero      <<<2, 256, 0, stream>>>(bucket_cnt, NB);
    k_bhist     <<<PBLK, 256, 0, stream>>>(dst, bucket_cnt, E, NB);
    k_bscan     <<<1, 512, 0, stream>>>(bucket_cnt, bucket_base, cursor, NB);
    k_place     <<<PBLK, 256, 0, stream>>>(src, dst, cursor, bedges, E, NB);
    k_bdeg_dinv <<<NB, 256, 0, stream>>>(bucket_base, bucket_cnt, bedges, dinv, n);
    k_gemm1     <<<(n + 255) / 256, 256, 0, stream>>>(x, W1, dinv, h1s, n);
    k_agg1      <<<NB, 512, 0, stream>>>(bucket_base, bucket_cnt, bedges, h1s, dinv, agg1, n);
    k_layer2    <<<(n + 255) / 256, 256, 0, stream>>>(agg1, b1, W2, dinv, h2s, n);
    k_agg2      <<<NB, 512, 0, stream>>>(bucket_base, bucket_cnt, bedges, h2s, dinv, b2, out, n);
}

// Round 4
// 940.429 us; speedup vs baseline: 1.0094x; 1.0094x over previous
//
#include <hip/hip_runtime.h>

#define F_IN 512
#define F_HID 16
#define F_OUT 7
#define BUCKET 128          // nodes per bucket
#define LB 7                // log2(BUCKET)
#define TRASH 128           // LDS trash row for sentinel pad edges
#define PADV 128            // packed sentinel: src=0, dl=TRASH
#define CHUNK 8192          // edges per partition block
#define AST 17              // LDS pad stride, 16-col tile
#define AST2 9              // LDS pad stride, 8-col tile
#define MAXNB 1024          // max buckets supported by scan/hist

// ---------------- zero int array ----------------
__global__ void k_zero(int* __restrict__ p, int n) {
    int i = blockIdx.x * blockDim.x + threadIdx.x;
    if (i < n) p[i] = 0;
}

// ---------------- bucket histogram (per-block LDS, then global merge) ----------------
__global__ void k_bhist(const int* __restrict__ dst, int* __restrict__ bucket_cnt, int E, int NB) {
    __shared__ int hist[MAXNB];
    int t = threadIdx.x;
    for (int i = t; i < NB; i += 256) hist[i] = 0;
    __syncthreads();
    int base = blockIdx.x * CHUNK;
#pragma unroll
    for (int i = 0; i < CHUNK / 256; ++i) {
        int e = base + i * 256 + t;
        if (e < E) atomicAdd(&hist[dst[e] >> LB], 1);
    }
    __syncthreads();
    for (int i = t; i < NB; i += 256)
        if (hist[i]) atomicAdd(&bucket_cnt[i], hist[i]);
}

// -------- exclusive scan of 4-aligned bucket counts + write sentinel pads --------
__global__ void k_bscan(const int* __restrict__ bucket_cnt, int* __restrict__ bucket_base,
                        int* __restrict__ cursor, int* __restrict__ bedges, int NB) {
    __shared__ int sm[MAXNB];
    int t = threadIdx.x;                       // 1024 threads
    int c = (t < NB) ? bucket_cnt[t] : 0;
    int ca = (c + 3) & ~3;                     // segment length padded to 4
    sm[t] = ca;
    __syncthreads();
    for (int off = 1; off < MAXNB; off <<= 1) {
        int v = sm[t];
        int add = (t >= off) ? sm[t - off] : 0;
        __syncthreads();
        sm[t] = v + add;
        __syncthreads();
    }
    if (t < NB) {
        int base = sm[t] - ca;                 // exclusive prefix (4-aligned)
        bucket_base[t] = base;
        cursor[t] = base;
        for (int i = c; i < ca; ++i) bedges[base + i] = PADV;   // sentinel tail
    }
}

// ---------------- partition: segmented placement of packed edges ----------------
__global__ void k_place(const int* __restrict__ src, const int* __restrict__ dst,
                        int* __restrict__ cursor, int* __restrict__ bedges, int E, int NB) {
    __shared__ int hist[MAXNB];
    __shared__ int lcur[MAXNB];
    int t = threadIdx.x;
    for (int i = t; i < NB; i += 256) hist[i] = 0;
    __syncthreads();
    int base = blockIdx.x * CHUNK;
#pragma unroll
    for (int i = 0; i < CHUNK / 256; ++i) {
        int e = base + i * 256 + t;
        if (e < E) atomicAdd(&hist[dst[e] >> LB], 1);
    }
    __syncthreads();
    for (int i = t; i < NB; i += 256)
        lcur[i] = hist[i] ? atomicAdd(&cursor[i], hist[i]) : 0;
    __syncthreads();
#pragma unroll
    for (int i = 0; i < CHUNK / 256; ++i) {
        int e = base + i * 256 + t;
        if (e < E) {
            int d = dst[e];
            int b = d >> LB;
            int pos = atomicAdd(&lcur[b], 1);
            bedges[pos] = (src[e] << 8) | (d & (BUCKET - 1));  // src<2^17, 8-bit dl
        }
    }
}

// ---------------- per-bucket degree histogram -> dinv ----------------
__global__ void k_bdeg_dinv(const int* __restrict__ bucket_base, const int* __restrict__ bucket_cnt,
                            const int* __restrict__ bedges, float* __restrict__ dinv, int n) {
    __shared__ int cnt[TRASH + 4];             // index 128 absorbs sentinels
    int b = blockIdx.x, t = threadIdx.x;       // 256 threads
    for (int i = t; i < TRASH + 4; i += 256) cnt[i] = 0;
    __syncthreads();
    int start = bucket_base[b], ne = bucket_cnt[b];
    int nq = (ne + 3) >> 2;
    for (int qi = t; qi < nq; qi += 256) {
        int4 q = *(const int4*)(bedges + start + (qi << 2));
        atomicAdd(&cnt[q.x & 255], 1);
        atomicAdd(&cnt[q.y & 255], 1);
        atomicAdd(&cnt[q.z & 255], 1);
        atomicAdd(&cnt[q.w & 255], 1);
    }
    __syncthreads();
    int node = b * BUCKET + t;
    if (t < BUCKET && node < n) dinv[node] = rsqrtf((float)(cnt[t] + 1));  // +1 self-loop
}

// ---------------- GEMM1: h1s = dinv[r] * (x @ W1), one row per thread ----------------
__global__ void k_gemm1(const float* __restrict__ x, const float* __restrict__ W,
                        const float* __restrict__ dinv, float* __restrict__ h1s, int n) {
    int r = blockIdx.x * blockDim.x + threadIdx.x;
    if (r >= n) return;
    float acc[F_HID];
#pragma unroll
    for (int c = 0; c < F_HID; ++c) acc[c] = 0.0f;
    const float4* xr = (const float4*)(x + (size_t)r * F_IN);
    for (int k4 = 0; k4 < F_IN / 4; ++k4) {
        float4 xv = xr[k4];
        int k = k4 * 4;
#pragma unroll
        for (int c = 0; c < F_HID; ++c) {
            acc[c] = fmaf(xv.x, W[(k + 0) * F_HID + c], acc[c]);
            acc[c] = fmaf(xv.y, W[(k + 1) * F_HID + c], acc[c]);
            acc[c] = fmaf(xv.z, W[(k + 2) * F_HID + c], acc[c]);
            acc[c] = fmaf(xv.w, W[(k + 3) * F_HID + c], acc[c]);
        }
    }
    float dv = dinv[r];
    float4* o = (float4*)(h1s + (size_t)r * F_HID);
    o[0] = make_float4(dv * acc[0], dv * acc[1], dv * acc[2], dv * acc[3]);
    o[1] = make_float4(dv * acc[4], dv * acc[5], dv * acc[6], dv * acc[7]);
    o[2] = make_float4(dv * acc[8], dv * acc[9], dv * acc[10], dv * acc[11]);
    o[3] = make_float4(dv * acc[12], dv * acc[13], dv * acc[14], dv * acc[15]);
}

// ------ agg layer 1: block(1024)/bucket, int4 edge loads, 4 gathers in flight ------
__global__ __launch_bounds__(1024) void k_agg1(
        const int* __restrict__ bucket_base, const int* __restrict__ bucket_cnt,
        const int* __restrict__ bedges, const float* __restrict__ h1s,
        const float* __restrict__ dinv, float* __restrict__ agg1, int n) {
    __shared__ float acc[(BUCKET + 1) * AST];       // row 128 = trash
    int b = blockIdx.x, t = threadIdx.x;
    for (int i = t; i < (BUCKET + 1) * AST; i += 1024) acc[i] = 0.0f;
    __syncthreads();
    int start = bucket_base[b], ne = bucket_cnt[b];
    int c = t & 15, g = t >> 4;                     // 64 groups of 16 lanes
    int nq = (ne + 3) >> 2;
    for (int qi = g; qi < nq; qi += 64) {
        int4 q = *(const int4*)(bedges + start + (qi << 2));
        float v0 = h1s[(size_t)(q.x >> 8) * F_HID + c];
        float v1 = h1s[(size_t)(q.y >> 8) * F_HID + c];
        float v2 = h1s[(size_t)(q.z >> 8) * F_HID + c];
        float v3 = h1s[(size_t)(q.w >> 8) * F_HID + c];
        atomicAdd(&acc[(q.x & 255) * AST + c], v0);
        atomicAdd(&acc[(q.y & 255) * AST + c], v1);
        atomicAdd(&acc[(q.z & 255) * AST + c], v2);
        atomicAdd(&acc[(q.w & 255) * AST + c], v3);
    }
    __syncthreads();
    int nodebase = b * BUCKET;
    for (int i = t; i < BUCKET * F_HID; i += 1024) {
        int row = i >> 4, cc = i & 15;
        int node = nodebase + row;
        if (node < n)
            agg1[(size_t)node * F_HID + cc] =
                dinv[node] * (acc[row * AST + cc] + h1s[(size_t)node * F_HID + cc]);
    }
}

// ---------------- relu+bias1+GEMM2, h2s = dinv * h2 (stride 8, col7 = 0) --------------
__global__ void k_layer2(const float* __restrict__ agg1, const float* __restrict__ b1,
                         const float* __restrict__ W2, const float* __restrict__ dinv,
                         float* __restrict__ h2s, int n) {
    int r = blockIdx.x * blockDim.x + threadIdx.x;
    if (r >= n) return;
    float z[F_HID];
    const float4* ai = (const float4*)(agg1 + (size_t)r * F_HID);
#pragma unroll
    for (int q = 0; q < 4; ++q) {
        float4 v = ai[q];
        z[q * 4 + 0] = fmaxf(v.x + b1[q * 4 + 0], 0.0f);
        z[q * 4 + 1] = fmaxf(v.y + b1[q * 4 + 1], 0.0f);
        z[q * 4 + 2] = fmaxf(v.z + b1[q * 4 + 2], 0.0f);
        z[q * 4 + 3] = fmaxf(v.w + b1[q * 4 + 3], 0.0f);
    }
    float h[F_OUT];
#pragma unroll
    for (int c = 0; c < F_OUT; ++c) h[c] = 0.0f;
#pragma unroll
    for (int k = 0; k < F_HID; ++k)
#pragma unroll
        for (int c = 0; c < F_OUT; ++c)
            h[c] = fmaf(z[k], W2[k * F_OUT + c], h[c]);
    float dv = dinv[r];
    float4* o = (float4*)(h2s + (size_t)r * 8);
    o[0] = make_float4(dv * h[0], dv * h[1], dv * h[2], dv * h[3]);
    o[1] = make_float4(dv * h[4], dv * h[5], dv * h[6], 0.0f);
}

// ------ agg layer 2: block(1024)/bucket, 8 lanes/edge, writes final out ------
__global__ __launch_bounds__(1024) void k_agg2(
        const int* __restrict__ bucket_base, const int* __restrict__ bucket_cnt,
        const int* __restrict__ bedges, const float* __restrict__ h2s,
        const float* __restrict__ dinv, const float* __restrict__ b2,
        float* __restrict__ out, int n) {
    __shared__ float acc[(BUCKET + 1) * AST2];      // row 128 = trash
    int b = blockIdx.x, t = threadIdx.x;
    for (int i = t; i < (BUCKET + 1) * AST2; i += 1024) acc[i] = 0.0f;
    __syncthreads();
    int start = bucket_base[b], ne = bucket_cnt[b];
    int c = t & 7, g = t >> 3;                      // 128 groups of 8 lanes
    int nq = (ne + 3) >> 2;
    for (int qi = g; qi < nq; qi += 128) {
        int4 q = *(const int4*)(bedges + start + (qi << 2));
        float v0 = h2s[(size_t)(q.x >> 8) * 8 + c];
        float v1 = h2s[(size_t)(q.y >> 8) * 8 + c];
        float v2 = h2s[(size_t)(q.z >> 8) * 8 + c];
        float v3 = h2s[(size_t)(q.w >> 8) * 8 + c];
        atomicAdd(&acc[(q.x & 255) * AST2 + c], v0);
        atomicAdd(&acc[(q.y & 255) * AST2 + c], v1);
        atomicAdd(&acc[(q.z & 255) * AST2 + c], v2);
        atomicAdd(&acc[(q.w & 255) * AST2 + c], v3);
    }
    __syncthreads();
    int nodebase = b * BUCKET;
    for (int i = t; i < BUCKET * 8; i += 1024) {
        int row = i >> 3, cc = i & 7;
        int node = nodebase + row;
        if (node < n && cc < F_OUT)
            out[(size_t)node * F_OUT + cc] =
                dinv[node] * (acc[row * AST2 + cc] + h2s[(size_t)node * 8 + cc]) + b2[cc];
    }
}

extern "C" void kernel_launch(void* const* d_in, const int* in_sizes, int n_in,
                              void* d_out, int out_size, void* d_ws, size_t ws_size,
                              hipStream_t stream) {
    const float* x  = (const float*)d_in[0];
    const int*   ei = (const int*)d_in[1];      // int64 in source but JAX x64 off -> int32
    const float* W1 = (const float*)d_in[2];
    const float* b1 = (const float*)d_in[3];
    const float* W2 = (const float*)d_in[4];
    const float* b2 = (const float*)d_in[5];
    float* out = (float*)d_out;

    const int n = in_sizes[0] / F_IN;       // 100000
    const int E = in_sizes[1] / 2;          // 3200000
    const int* src = ei;
    const int* dst = ei + E;

    const int NB = (n + BUCKET - 1) / BUCKET;   // 782 (must be <= MAXNB)
    const int PBLK = (E + CHUNK - 1) / CHUNK;   // 391 partition blocks

    // workspace layout
    size_t Np = ((size_t)n + 3) & ~(size_t)3;
    size_t Ep = ((size_t)E + 4 * MAXNB + 3) & ~(size_t)3;   // room for 4-align pads
    char* ws = (char*)d_ws;
    int*   bucket_cnt  = (int*)ws;              ws += MAXNB * 4;
    int*   bucket_base = (int*)ws;              ws += MAXNB * 4;
    int*   cursor      = (int*)ws;              ws += MAXNB * 4;
    float* dinv        = (float*)ws;            ws += Np * 4;
    int*   bedges      = (int*)ws;              ws += Ep * 4;
    float* h1s         = (float*)ws;            ws += Np * F_HID * 4;
    float* agg1        = (float*)ws;            ws += Np * F_HID * 4;
    float* h2s         = h1s;                   // h1s dead after k_agg1

    k_zero      <<<4, 256, 0, stream>>>(bucket_cnt, NB);
    k_bhist     <<<PBLK, 256, 0, stream>>>(dst, bucket_cnt, E, NB);
    k_bscan     <<<1, 1024, 0, stream>>>(bucket_cnt, bucket_base, cursor, bedges, NB);
    k_place     <<<PBLK, 256, 0, stream>>>(src, dst, cursor, bedges, E, NB);
    k_bdeg_dinv <<<NB, 256, 0, stream>>>(bucket_base, bucket_cnt, bedges, dinv, n);
    k_gemm1     <<<(n + 255) / 256, 256, 0, stream>>>(x, W1, dinv, h1s, n);
    k_agg1      <<<NB, 1024, 0, stream>>>(bucket_base, bucket_cnt, bedges, h1s, dinv, agg1, n);
    k_layer2    <<<(n + 255) / 256, 256, 0, stream>>>(agg1, b1, W2, dinv, h2s, n);
    k_agg2      <<<NB, 1024, 0, stream>>>(bucket_base, bucket_cnt, bedges, h2s, dinv, b2, out, n);
}